// Round 1
// baseline (1472.499 us; speedup 1.0000x reference)
//
#include <hip/hip_runtime.h>
#include <math.h>

#define Bdim 4
#define Lseq 4096
#define INDIM 512
#define DH 64
#define OUTD 512
#define NCH 32          // q-chunks for column stats (128 q each)
#define QCH 128
#define KSPL 4          // k-range splits for PV accumulation
#define SCALE 0.125f    // 1/sqrt(64)

// ---------------- Kernel A: q/k/v = x @ W + b ----------------
__global__ __launch_bounds__(256) void qkv_proj(const float* __restrict__ x,
                                                const float* __restrict__ W,
                                                const float* __restrict__ bias,
                                                float* __restrict__ out) {
    int tid = threadIdx.x;
    int d = tid & 63;
    int r = tid >> 6;                       // 0..3
    int row = blockIdx.x * 4 + r;           // 0..B*L-1
    const float4* x4 = reinterpret_cast<const float4*>(x + (size_t)row * INDIM);
    float acc = bias[d];
#pragma unroll 8
    for (int kk4 = 0; kk4 < INDIM / 4; ++kk4) {
        float4 xv = x4[kk4];
        int kk = kk4 * 4;
        acc += xv.x * W[(kk + 0) * DH + d];
        acc += xv.y * W[(kk + 1) * DH + d];
        acc += xv.z * W[(kk + 2) * DH + d];
        acc += xv.w * W[(kk + 3) * DH + d];
    }
    out[(size_t)row * DH + d] = acc;
}

// ------- Kernel B1: per-(column, q-chunk) partial max / sumexp -------
// softmax is over the QUERY axis: stats are per (b, k) column.
__global__ __launch_bounds__(256) void col_stats_partial(
        const float* __restrict__ qg, const float* __restrict__ kg,
        float* __restrict__ pm, float* __restrict__ pl) {
    __shared__ float qs[QCH * DH];          // 32 KB
    int tid = threadIdx.x;
    int b = blockIdx.y;
    int ch = blockIdx.z;
    int kk = blockIdx.x * 256 + tid;        // this thread's column

    // stage q chunk [128 x 64] (coalesced float4)
    const float4* qsrc = reinterpret_cast<const float4*>(
        qg + ((size_t)b * Lseq + (size_t)ch * QCH) * DH);
    float4* qdst = reinterpret_cast<float4*>(qs);
#pragma unroll
    for (int j = 0; j < (QCH * DH / 4) / 256; ++j)   // 8
        qdst[j * 256 + tid] = qsrc[j * 256 + tid];

    // this thread's k-column vector into registers
    float kreg[DH];
    const float4* ksrc = reinterpret_cast<const float4*>(
        kg + ((size_t)b * Lseq + kk) * DH);
#pragma unroll
    for (int j = 0; j < DH / 4; ++j) {
        float4 kv = ksrc[j];
        kreg[4 * j + 0] = kv.x; kreg[4 * j + 1] = kv.y;
        kreg[4 * j + 2] = kv.z; kreg[4 * j + 3] = kv.w;
    }
    __syncthreads();

    float m = -1e30f, l = 0.f;
    for (int ql = 0; ql < QCH; ++ql) {
        const float4* qrow = reinterpret_cast<const float4*>(qs + ql * DH);
        float s = 0.f;
#pragma unroll
        for (int j = 0; j < DH / 4; ++j) {
            float4 qv = qrow[j];        // broadcast read (all lanes same addr)
            s += qv.x * kreg[4 * j + 0] + qv.y * kreg[4 * j + 1]
               + qv.z * kreg[4 * j + 2] + qv.w * kreg[4 * j + 3];
        }
        s *= SCALE;
        float nm = fmaxf(m, s);
        l = l * __expf(m - nm) + __expf(s - nm);
        m = nm;
    }
    size_t col = (size_t)b * Lseq + kk;
    pm[col * NCH + ch] = m;
    pl[col * NCH + ch] = l;
}

// ------- Kernel B2: merge partial stats -> m[col], 1/l[col] -------
__global__ __launch_bounds__(256) void col_stats_final(
        const float* __restrict__ pm, const float* __restrict__ pl,
        float* __restrict__ mw, float* __restrict__ rlw) {
    int col = blockIdx.x * 256 + threadIdx.x;
    float m = -1e30f, l = 0.f;
#pragma unroll 8
    for (int ch = 0; ch < NCH; ++ch) {
        float mm = pm[(size_t)col * NCH + ch];
        float ll = pl[(size_t)col * NCH + ch];
        float nm = fmaxf(m, mm);
        l = l * __expf(m - nm) + ll * __expf(mm - nm);
        m = nm;
    }
    mw[col] = m;
    rlw[col] = 1.0f / l;
}

// ------- Kernel C: recompute S, write attention, accumulate PV partials -------
// grid: (L/64 q-tiles, B, KSPL). Block: 256 threads.
__global__ __launch_bounds__(256) void attn_pv(
        const float* __restrict__ qg, const float* __restrict__ kg,
        const float* __restrict__ vg, const float* __restrict__ mw,
        const float* __restrict__ rlw, float* __restrict__ att,
        float* __restrict__ opart) {
    __shared__ float qs[64 * DH];       // 16 KB, broadcast-read
    __shared__ float als[64 * 68];      // 17.4 KB, pad 68: (4k+d)%32 -> 2-way
    __shared__ float vls[64 * 68];      // 17.4 KB

    int tid = threadIdx.x;
    int b = blockIdx.y;
    int q0 = blockIdx.x * 64;
    int split = blockIdx.z;
    int lane = tid & 63;                // phase1: k-col; phase2: d
    int rg = tid >> 6;                  // 0..3 row group

    // stage q tile [64 x 64]
    {
        const float4* qsrc = reinterpret_cast<const float4*>(
            qg + ((size_t)b * Lseq + q0) * DH);
        float4* qdst = reinterpret_cast<float4*>(qs);
#pragma unroll
        for (int j = 0; j < (64 * DH / 4) / 256; ++j)   // 4
            qdst[j * 256 + tid] = qsrc[j * 256 + tid];
    }

    float o[16];
#pragma unroll
    for (int i = 0; i < 16; ++i) o[i] = 0.f;

    for (int kt = 0; kt < 1024 / 64; ++kt) {   // 16 k-subtiles of 64
        int kbase = split * 1024 + kt * 64;
        __syncthreads();  // prev phase2 done reading als/vls (also covers qs stage)

        // stage v tile [64 x 64] with pad-68 (scalar stores)
        {
            const float* vsrc = vg + ((size_t)b * Lseq + kbase) * DH;
#pragma unroll
            for (int j = 0; j < 16; ++j) {
                int idx = j * 256 + tid;            // 0..4095
                vls[(idx >> 6) * 68 + (idx & 63)] = vsrc[idx];
            }
        }

        // phase 1: S = q @ k^T, A = exp(S-m)/l, write global + LDS
        float kreg[DH];
        {
            const float4* ksrc = reinterpret_cast<const float4*>(
                kg + ((size_t)b * Lseq + kbase + lane) * DH);
#pragma unroll
            for (int j = 0; j < DH / 4; ++j) {
                float4 kv = ksrc[j];
                kreg[4 * j + 0] = kv.x; kreg[4 * j + 1] = kv.y;
                kreg[4 * j + 2] = kv.z; kreg[4 * j + 3] = kv.w;
            }
        }
        float mc = mw[(size_t)b * Lseq + kbase + lane];
        float rlc = rlw[(size_t)b * Lseq + kbase + lane];
#pragma unroll
        for (int i = 0; i < 16; ++i) {
            int ql = rg * 16 + i;
            const float4* qrow = reinterpret_cast<const float4*>(qs + ql * DH);
            float s = 0.f;
#pragma unroll
            for (int j = 0; j < DH / 4; ++j) {
                float4 qv = qrow[j];   // broadcast
                s += qv.x * kreg[4 * j + 0] + qv.y * kreg[4 * j + 1]
                   + qv.z * kreg[4 * j + 2] + qv.w * kreg[4 * j + 3];
            }
            float a = __expf(s * SCALE - mc) * rlc;
            att[((size_t)b * Lseq + q0 + ql) * Lseq + kbase + lane] = a;  // coalesced
            als[ql * 68 + lane] = a;
        }
        __syncthreads();

        // phase 2: O[ql][d] += A[ql][k] * V[k][d]   (lane = d now)
#pragma unroll
        for (int i = 0; i < 16; ++i) {
            int ql = rg * 16 + i;
            float acc = o[i];
#pragma unroll 16
            for (int kkk = 0; kkk < 64; ++kkk)
                acc += als[ql * 68 + kkk] * vls[kkk * 68 + lane];
            o[i] = acc;
        }
    }

    // write O partial for this k-split
#pragma unroll
    for (int i = 0; i < 16; ++i) {
        int ql = rg * 16 + i;
        size_t R = (size_t)b * Lseq + q0 + ql;
        opart[((size_t)split * Bdim * Lseq + R) * DH + lane] = o[i];  // coalesced
    }
}

// ------- Kernel D: reduce k-split partials + output projection -------
// grid: (B*L/16 row-groups, 4 o-quarters). Block 256.
__global__ __launch_bounds__(256) void out_proj(
        const float* __restrict__ opart, const float* __restrict__ Wo,
        const float* __restrict__ bo, float* __restrict__ out) {
    __shared__ float os[16 * DH];       // 4 KB
    __shared__ float wos[DH * 128];     // 32 KB (o-quarter of Wo)
    int tid = threadIdx.x;
    int rg = blockIdx.x;                // 16 rows each
    int oq = blockIdx.y;                // o-quarter

    // stage Wo[:, oq*128 : +128]
#pragma unroll
    for (int j = 0; j < (DH * 128) / 256; ++j) {     // 32
        int idx = j * 256 + tid;
        int dd = idx >> 7, oo = idx & 127;
        wos[idx] = Wo[(size_t)dd * OUTD + oq * 128 + oo];
    }
    // stage 16 rows of O (sum of KSPL partials)
#pragma unroll
    for (int j = 0; j < (16 * DH) / 256; ++j) {      // 4
        int idx = j * 256 + tid;                     // rr = idx>>6, dd = idx&63
        size_t R = (size_t)rg * 16 + (idx >> 6);
        float s = 0.f;
#pragma unroll
        for (int sp = 0; sp < KSPL; ++sp)
            s += opart[((size_t)sp * Bdim * Lseq + R) * DH + (idx & 63)];
        os[idx] = s;
    }
    __syncthreads();

    int ol = tid & 127;
    int rp = tid >> 7;                  // 0..1
    float bias = bo[oq * 128 + ol];
#pragma unroll
    for (int j = 0; j < 8; ++j) {
        int rr = rp * 8 + j;
        float acc = bias;
#pragma unroll 16
        for (int dd = 0; dd < DH; ++dd)
            acc += os[rr * DH + dd] * wos[dd * 128 + ol];
        size_t R = (size_t)rg * 16 + rr;
        out[R * OUTD + oq * 128 + ol] = acc;        // coalesced
    }
}

extern "C" void kernel_launch(void* const* d_in, const int* in_sizes, int n_in,
                              void* d_out, int out_size, void* d_ws, size_t ws_size,
                              hipStream_t stream) {
    const float* x  = (const float*)d_in[0];
    const float* Wq = (const float*)d_in[1];
    const float* bq = (const float*)d_in[2];
    const float* Wk = (const float*)d_in[3];
    const float* bk = (const float*)d_in[4];
    const float* Wv = (const float*)d_in[5];
    const float* bv = (const float*)d_in[6];
    const float* Wo = (const float*)d_in[7];
    const float* bo = (const float*)d_in[8];

    float* out = (float*)d_out;                         // [B,L,OUTD] first
    float* att = out + (size_t)Bdim * Lseq * OUTD;      // then [B,L,L] attention

    float* ws = (float*)d_ws;
    size_t qkv_n = (size_t)Bdim * Lseq * DH;            // 1,048,576
    float* qw  = ws;
    float* kw  = qw + qkv_n;
    float* vw  = kw + qkv_n;
    float* pm  = vw + qkv_n;                            // B*L*NCH
    float* pl  = pm + (size_t)Bdim * Lseq * NCH;
    float* mw  = pl + (size_t)Bdim * Lseq * NCH;        // B*L
    float* rlw = mw + (size_t)Bdim * Lseq;
    float* opart = rlw + (size_t)Bdim * Lseq;           // KSPL*B*L*DH

    qkv_proj<<<dim3(Bdim * Lseq / 4), 256, 0, stream>>>(x, Wq, bq, qw);
    qkv_proj<<<dim3(Bdim * Lseq / 4), 256, 0, stream>>>(x, Wk, bk, kw);
    qkv_proj<<<dim3(Bdim * Lseq / 4), 256, 0, stream>>>(x, Wv, bv, vw);
    col_stats_partial<<<dim3(Lseq / 256, Bdim, NCH), 256, 0, stream>>>(qw, kw, pm, pl);
    col_stats_final<<<dim3(Bdim * Lseq / 256), 256, 0, stream>>>(pm, pl, mw, rlw);
    attn_pv<<<dim3(Lseq / 64, Bdim, KSPL), 256, 0, stream>>>(qw, kw, vw, mw, rlw, att, opart);
    out_proj<<<dim3(Bdim * Lseq / 16, 4), 256, 0, stream>>>(opart, Wo, bo, out);
}

// Round 2
// 522.436 us; speedup vs baseline: 2.8185x; 2.8185x over previous
//
#include <hip/hip_runtime.h>
#include <hip/hip_fp16.h>
#include <math.h>

#define Bdim 4
#define Lseq 4096
#define INDIM 512
#define DH 64
#define OUTD 512
#define SCALE 0.125f
#define KSPL 8
#define QSPL 4
#define BL (Bdim * Lseq)

typedef _Float16 f16;
typedef _Float16 h8 __attribute__((ext_vector_type(8)));
typedef float f4 __attribute__((ext_vector_type(4)));

#define MFMA(a, b, c) __builtin_amdgcn_mfma_f32_16x16x32_f16(a, b, c, 0, 0, 0)

// ---------------- fp32 tiled projection, fp16 output (q pre-scaled) -------------
__global__ __launch_bounds__(256) void proj_h(const float* __restrict__ x,
                                              const float* __restrict__ W,
                                              const float* __restrict__ bias,
                                              f16* __restrict__ out, float scale) {
    __shared__ float xT[64 * 68];   // [k][row], stride 68
    __shared__ float Ws[64 * 68];   // [k][d],   stride 68
    int t = threadIdx.x;
    int row0 = blockIdx.x * 64;
    int r4 = t >> 4;                // 0..15
    int c4 = t & 15;                // 0..15
    float acc[4][4] = {};
    for (int kc = 0; kc < INDIM; kc += 64) {
        __syncthreads();
        {   // stage x[64 rows][64 k] transposed
            int row = t >> 2, kq = (t & 3) * 16;
            const float4* src = (const float4*)(x + (size_t)(row0 + row) * INDIM + kc + kq);
            float tmp[16];
#pragma unroll
            for (int i = 0; i < 4; ++i) {
                float4 v = src[i];
                tmp[4*i+0] = v.x; tmp[4*i+1] = v.y; tmp[4*i+2] = v.z; tmp[4*i+3] = v.w;
            }
#pragma unroll
            for (int j = 0; j < 16; ++j) xT[(kq + j) * 68 + row] = tmp[j];
        }
        {   // stage W[64 k][64 d]
            int k = t >> 2, dq = (t & 3) * 16;
            const float4* src = (const float4*)(W + (size_t)(kc + k) * DH + dq);
#pragma unroll
            for (int i = 0; i < 4; ++i)
                *(float4*)(Ws + k * 68 + dq + 4 * i) = src[i];
        }
        __syncthreads();
#pragma unroll 8
        for (int k = 0; k < 64; ++k) {
            f4 xv = *(f4*)(xT + k * 68 + r4 * 4);
            f4 wv = *(f4*)(Ws + k * 68 + c4 * 4);
#pragma unroll
            for (int i = 0; i < 4; ++i)
#pragma unroll
                for (int j = 0; j < 4; ++j) acc[i][j] += xv[i] * wv[j];
        }
    }
#pragma unroll
    for (int i = 0; i < 4; ++i) {
        size_t row = row0 + r4 * 4 + i;
#pragma unroll
        for (int j = 0; j < 4; ++j) {
            int d = c4 * 4 + j;
            out[row * DH + d] = (f16)((acc[i][j] + bias[d]) * scale);
        }
    }
}

__global__ __launch_bounds__(256) void proj_f(const float* __restrict__ x,
                                              const float* __restrict__ W,
                                              const float* __restrict__ bias,
                                              float* __restrict__ out) {
    __shared__ float xT[64 * 68];
    __shared__ float Ws[64 * 68];
    int t = threadIdx.x;
    int row0 = blockIdx.x * 64;
    int r4 = t >> 4, c4 = t & 15;
    float acc[4][4] = {};
    for (int kc = 0; kc < INDIM; kc += 64) {
        __syncthreads();
        {
            int row = t >> 2, kq = (t & 3) * 16;
            const float4* src = (const float4*)(x + (size_t)(row0 + row) * INDIM + kc + kq);
            float tmp[16];
#pragma unroll
            for (int i = 0; i < 4; ++i) {
                float4 v = src[i];
                tmp[4*i+0] = v.x; tmp[4*i+1] = v.y; tmp[4*i+2] = v.z; tmp[4*i+3] = v.w;
            }
#pragma unroll
            for (int j = 0; j < 16; ++j) xT[(kq + j) * 68 + row] = tmp[j];
        }
        {
            int k = t >> 2, dq = (t & 3) * 16;
            const float4* src = (const float4*)(W + (size_t)(kc + k) * DH + dq);
#pragma unroll
            for (int i = 0; i < 4; ++i)
                *(float4*)(Ws + k * 68 + dq + 4 * i) = src[i];
        }
        __syncthreads();
#pragma unroll 8
        for (int k = 0; k < 64; ++k) {
            f4 xv = *(f4*)(xT + k * 68 + r4 * 4);
            f4 wv = *(f4*)(Ws + k * 68 + c4 * 4);
#pragma unroll
            for (int i = 0; i < 4; ++i)
#pragma unroll
                for (int j = 0; j < 4; ++j) acc[i][j] += xv[i] * wv[j];
        }
    }
#pragma unroll
    for (int i = 0; i < 4; ++i) {
        size_t row = row0 + r4 * 4 + i;
#pragma unroll
        for (int j = 0; j < 4; ++j) {
            int d = c4 * 4 + j;
            out[row * DH + d] = acc[i][j] + bias[d];
        }
    }
}

// ---------------- v fp32 -> vt fp16 transposed [b][d][k] ----------------
__global__ __launch_bounds__(256) void vtrans(const float* __restrict__ v32,
                                              f16* __restrict__ vt) {
    __shared__ float tile[64 * 65];
    int t = threadIdx.x;
    int b = blockIdx.y, k0 = blockIdx.x * 64;
#pragma unroll
    for (int i = 0; i < 4; ++i) {
        int lin = i * 256 + t;
        int row = lin >> 4, c4 = (lin & 15) * 4;
        float4 v = *(const float4*)(v32 + ((size_t)b * Lseq + k0 + row) * DH + c4);
        tile[row * 65 + c4 + 0] = v.x;
        tile[row * 65 + c4 + 1] = v.y;
        tile[row * 65 + c4 + 2] = v.z;
        tile[row * 65 + c4 + 3] = v.w;
    }
    __syncthreads();
    int d = t >> 2, kq = (t & 3) * 16;
#pragma unroll
    for (int i = 0; i < 2; ++i) {
        h8 pack;
#pragma unroll
        for (int j = 0; j < 8; ++j) pack[j] = (f16)tile[(kq + i * 8 + j) * 65 + d];
        *(h8*)(vt + ((size_t)b * DH + d) * Lseq + k0 + kq + i * 8) = pack;
    }
}

// ---------------- pass 1: column sums of exp(s) via MFMA (D = K·Q^T) ------------
__global__ __launch_bounds__(256) void col_stats(const f16* __restrict__ qh,
                                                 const f16* __restrict__ kh,
                                                 float* __restrict__ lsum) {
    __shared__ __align__(16) f16 qlds[32 * 72];
    int t = threadIdx.x;
    int w = t >> 6, lane = t & 63;
    int l15 = lane & 15, quad = lane >> 4;
    int b = blockIdx.y;
    int kblk = blockIdx.x * 64;
    int qbase = blockIdx.z * (Lseq / QSPL);

    int krow = kblk + w * 16 + l15;
    const h8* kr = (const h8*)(kh + ((size_t)b * Lseq + krow) * DH + quad * 8);
    h8 a0 = kr[0];
    h8 a1 = kr[4];      // +32 halves
    float lp[4] = {0.f, 0.f, 0.f, 0.f};

    for (int qs = 0; qs < Lseq / QSPL; qs += 32) {
        __syncthreads();
        {
            int row = t >> 3, c8 = t & 7;
            *(h8*)(qlds + row * 72 + c8 * 8) =
                *(const h8*)(qh + ((size_t)b * Lseq + qbase + qs + row) * DH + c8 * 8);
        }
        __syncthreads();
#pragma unroll
        for (int nt = 0; nt < 2; ++nt) {
            const f16* qp = qlds + (nt * 16 + l15) * 72 + quad * 8;
            h8 b0 = *(const h8*)qp;
            h8 b1 = *(const h8*)(qp + 32);
            f4 c = {0.f, 0.f, 0.f, 0.f};
            c = MFMA(a0, b0, c);
            c = MFMA(a1, b1, c);
#pragma unroll
            for (int reg = 0; reg < 4; ++reg) lp[reg] += __expf(c[reg]);
        }
    }
#pragma unroll
    for (int reg = 0; reg < 4; ++reg) {
        float v = lp[reg];
        v += __shfl_xor(v, 1);
        v += __shfl_xor(v, 2);
        v += __shfl_xor(v, 4);
        v += __shfl_xor(v, 8);
        if (l15 == 0)
            atomicAdd(&lsum[(size_t)b * Lseq + kblk + w * 16 + quad * 4 + reg], v);
    }
}

__global__ __launch_bounds__(256) void rlk(const float* __restrict__ lsum,
                                           float* __restrict__ rl) {
    int i = blockIdx.x * 256 + threadIdx.x;
    rl[i] = 1.0f / lsum[i];
}

// ------- pass 2: S via MFMA, A = exp(s)*rl -> att + LDS(fp16), PV via MFMA ------
__global__ __launch_bounds__(256) void attn_pv(const f16* __restrict__ qh,
                                               const f16* __restrict__ kh,
                                               const f16* __restrict__ vt,
                                               const float* __restrict__ rl,
                                               float* __restrict__ att,
                                               f16* __restrict__ opart) {
    __shared__ __align__(16) f16 klds[64 * 72];
    __shared__ __align__(16) f16 elds[4][32 * 80];
    int t = threadIdx.x;
    int w = t >> 6, lane = t & 63;
    int l15 = lane & 15, quad = lane >> 4;
    int b = blockIdx.y;
    int q0 = blockIdx.x * 128 + w * 32;
    int split = blockIdx.z;

    // persistent Q A-frags (q pre-scaled by 1/8)
    h8 aq[2][2];
#pragma unroll
    for (int mt = 0; mt < 2; ++mt) {
        const h8* qp = (const h8*)(qh + ((size_t)b * Lseq + q0 + mt * 16 + l15) * DH + quad * 8);
        aq[mt][0] = qp[0];
        aq[mt][1] = qp[4];
    }
    f4 o[2][4];
#pragma unroll
    for (int mt = 0; mt < 2; ++mt)
#pragma unroll
        for (int nt = 0; nt < 4; ++nt) o[mt][nt] = (f4){0.f, 0.f, 0.f, 0.f};

    const float* rlb = rl + (size_t)b * Lseq;
    f16* ew = elds[w];

    for (int kt = 0; kt < Lseq / KSPL; kt += 64) {
        int kbase = split * (Lseq / KSPL) + kt;
        __syncthreads();
#pragma unroll
        for (int i = 0; i < 2; ++i) {
            int lin = i * 256 + t;
            int row = lin >> 3, c8 = lin & 7;
            *(h8*)(klds + row * 72 + c8 * 8) =
                *(const h8*)(kh + ((size_t)b * Lseq + kbase + row) * DH + c8 * 8);
        }
        __syncthreads();

        h8 bk[4][2];
        float rlv[4];
#pragma unroll
        for (int nt = 0; nt < 4; ++nt) {
            const f16* kp = klds + (nt * 16 + l15) * 72 + quad * 8;
            bk[nt][0] = *(const h8*)kp;
            bk[nt][1] = *(const h8*)(kp + 32);
            rlv[nt] = rlb[kbase + nt * 16 + l15];
        }

#pragma unroll
        for (int mt = 0; mt < 2; ++mt)
#pragma unroll
            for (int nt = 0; nt < 4; ++nt) {
                f4 c = {0.f, 0.f, 0.f, 0.f};
                c = MFMA(aq[mt][0], bk[nt][0], c);
                c = MFMA(aq[mt][1], bk[nt][1], c);
#pragma unroll
                for (int reg = 0; reg < 4; ++reg) {
                    float a = __expf(c[reg]) * rlv[nt];
                    int qrow = mt * 16 + quad * 4 + reg;
                    att[((size_t)b * Lseq + q0 + qrow) * Lseq + kbase + nt * 16 + l15] = a;
                    ew[qrow * 80 + nt * 16 + l15] = (f16)a;
                }
            }

        // PV: O += A @ V   (A from per-wave LDS, V^T fp16 from global)
        h8 ae[2][2];
#pragma unroll
        for (int mt = 0; mt < 2; ++mt) {
            const f16* ep = ew + (mt * 16 + l15) * 80 + quad * 8;
            ae[mt][0] = *(const h8*)ep;
            ae[mt][1] = *(const h8*)(ep + 32);
        }
#pragma unroll
        for (int nt = 0; nt < 4; ++nt) {
            const h8* vp = (const h8*)(vt + ((size_t)b * DH + nt * 16 + l15) * Lseq + kbase + quad * 8);
            h8 bv0 = vp[0];
            h8 bv1 = vp[4];
            o[0][nt] = MFMA(ae[0][0], bv0, o[0][nt]);
            o[0][nt] = MFMA(ae[0][1], bv1, o[0][nt]);
            o[1][nt] = MFMA(ae[1][0], bv0, o[1][nt]);
            o[1][nt] = MFMA(ae[1][1], bv1, o[1][nt]);
        }
    }

#pragma unroll
    for (int mt = 0; mt < 2; ++mt)
#pragma unroll
        for (int nt = 0; nt < 4; ++nt)
#pragma unroll
            for (int reg = 0; reg < 4; ++reg) {
                size_t qrow = (size_t)b * Lseq + q0 + mt * 16 + quad * 4 + reg;
                opart[((size_t)split * BL + qrow) * DH + nt * 16 + l15] = (f16)o[mt][nt][reg];
            }
}

// ---------------- reduce k-split partials + output projection ----------------
__global__ __launch_bounds__(256) void out_proj(const f16* __restrict__ opart,
                                                const float* __restrict__ Wo,
                                                const float* __restrict__ bo,
                                                float* __restrict__ out) {
    __shared__ float os[16 * DH];
    __shared__ float wos[DH * 128];
    int t = threadIdx.x;
    int rg = blockIdx.x, oq = blockIdx.y;
#pragma unroll
    for (int j = 0; j < 32; ++j) {
        int idx = j * 256 + t;
        int dd = idx >> 7, oo = idx & 127;
        wos[idx] = Wo[(size_t)dd * OUTD + oq * 128 + oo];
    }
#pragma unroll
    for (int j = 0; j < 4; ++j) {
        int idx = j * 256 + t;
        size_t R = (size_t)rg * 16 + (idx >> 6);
        int dd = idx & 63;
        float s = 0.f;
#pragma unroll
        for (int sp = 0; sp < KSPL; ++sp)
            s += (float)opart[((size_t)sp * BL + R) * DH + dd];
        os[idx] = s;
    }
    __syncthreads();
    int ol = t & 127, rp = t >> 7;
    float bias = bo[oq * 128 + ol];
#pragma unroll
    for (int j = 0; j < 8; ++j) {
        int rr = rp * 8 + j;
        float acc = bias;
#pragma unroll 16
        for (int dd = 0; dd < DH; ++dd) acc += os[rr * DH + dd] * wos[dd * 128 + ol];
        out[((size_t)rg * 16 + rr) * OUTD + oq * 128 + ol] = acc;
    }
}

extern "C" void kernel_launch(void* const* d_in, const int* in_sizes, int n_in,
                              void* d_out, int out_size, void* d_ws, size_t ws_size,
                              hipStream_t stream) {
    const float* x  = (const float*)d_in[0];
    const float* Wq = (const float*)d_in[1];
    const float* bq = (const float*)d_in[2];
    const float* Wk = (const float*)d_in[3];
    const float* bk = (const float*)d_in[4];
    const float* Wv = (const float*)d_in[5];
    const float* bv = (const float*)d_in[6];
    const float* Wo = (const float*)d_in[7];
    const float* bo = (const float*)d_in[8];

    float* out = (float*)d_out;                         // [B,L,OUTD]
    float* att = out + (size_t)BL * OUTD;               // [B,L,L]

    char* ws = (char*)d_ws;
    f16*   qh    = (f16*)(ws + 0);                      // 2 MB
    f16*   kh    = (f16*)(ws + (size_t)(2 << 20));      // 2 MB
    float* v32   = (float*)(ws + (size_t)(4 << 20));    // 4 MB
    f16*   vt    = (f16*)(ws + (size_t)(8 << 20));      // 2 MB
    float* lsum  = (float*)(ws + (size_t)(10 << 20));   // 64 KB
    float* rlw   = (float*)(ws + (size_t)(10 << 20) + (1 << 16)); // 64 KB
    f16*   opart = (f16*)(ws + (size_t)(11 << 20));     // 16 MB

    proj_h<<<dim3(BL / 64), 256, 0, stream>>>(x, Wq, bq, qh, SCALE);
    proj_h<<<dim3(BL / 64), 256, 0, stream>>>(x, Wk, bk, kh, 1.0f);
    proj_f<<<dim3(BL / 64), 256, 0, stream>>>(x, Wv, bv, v32);
    vtrans<<<dim3(Lseq / 64, Bdim), 256, 0, stream>>>(v32, vt);
    hipMemsetAsync(lsum, 0, (size_t)BL * sizeof(float), stream);
    col_stats<<<dim3(Lseq / 64, Bdim, QSPL), 256, 0, stream>>>(qh, kh, lsum);
    rlk<<<dim3(BL / 256), 256, 0, stream>>>(lsum, rlw);
    attn_pv<<<dim3(Lseq / 128, Bdim, KSPL), 256, 0, stream>>>(qh, kh, vt, rlw, att, opart);
    out_proj<<<dim3(BL / 16, 4), 256, 0, stream>>>(opart, Wo, bo, out);
}